// Round 3
// baseline (169.566 us; speedup 1.0000x reference)
//
#include <hip/hip_runtime.h>

// Fused: h = x + residual; out = h * rsqrt(mean(h^2)+eps) * w, zero-padded
// to 4096 cols. d_out layout: out[16384][4096] fp32, then h[16384][3584] fp32.
// R2: non-temporal loads/stores on all streaming traffic.
// R3: phase-split — pass 1 is pure reads (x, res -> h in regs, sum h^2);
//     pass 2 is pure writes (h, out, pad) so HBM sees long same-direction
//     bursts instead of fine-grained read/write interleave.

#define M_ROWS 16384
#define DIM 3584
#define NOUT 4096
#define VEC4 (DIM / 4)          // 896 float4 per row
#define PAD4 ((NOUT - DIM) / 4) // 128 float4 of zeros per row
#define BLOCK 256
#define ITERS (VEC4 / BLOCK + 1) // 4 (last iter: threads 0..127 active)

__device__ __forceinline__ float4 nt_load4(const float4* p) {
    float4 v;
    v.x = __builtin_nontemporal_load(&p->x);
    v.y = __builtin_nontemporal_load(&p->y);
    v.z = __builtin_nontemporal_load(&p->z);
    v.w = __builtin_nontemporal_load(&p->w);
    return v;
}

__device__ __forceinline__ void nt_store4(float4* p, float4 v) {
    __builtin_nontemporal_store(v.x, &p->x);
    __builtin_nontemporal_store(v.y, &p->y);
    __builtin_nontemporal_store(v.z, &p->z);
    __builtin_nontemporal_store(v.w, &p->w);
}

__global__ __launch_bounds__(BLOCK) void fused_add_rmsnorm_pad(
    const float* __restrict__ x,
    const float* __restrict__ res,
    const float* __restrict__ w,
    float* __restrict__ out,   // [M][NOUT]
    float* __restrict__ hout)  // [M][DIM]
{
    const int row = blockIdx.x;
    const int tid = threadIdx.x;

    const float4* __restrict__ xr = reinterpret_cast<const float4*>(x + (size_t)row * DIM);
    const float4* __restrict__ rr = reinterpret_cast<const float4*>(res + (size_t)row * DIM);
    const float4* __restrict__ wv = reinterpret_cast<const float4*>(w);
    float4* __restrict__ hr = reinterpret_cast<float4*>(hout + (size_t)row * DIM);
    float4* __restrict__ orow = reinterpret_cast<float4*>(out + (size_t)row * NOUT);

    // Pass 1 (pure read): h = x + res kept in regs, accumulate sum(h^2).
    float4 h[ITERS];
    float ss = 0.0f;
#pragma unroll
    for (int it = 0; it < ITERS; ++it) {
        const int i = tid + it * BLOCK;
        if (i < VEC4) {
            const float4 a = nt_load4(&xr[i]);
            const float4 b = nt_load4(&rr[i]);
            float4 hv;
            hv.x = a.x + b.x;
            hv.y = a.y + b.y;
            hv.z = a.z + b.z;
            hv.w = a.w + b.w;
            h[it] = hv;
            ss += hv.x * hv.x + hv.y * hv.y + hv.z * hv.z + hv.w * hv.w;
        }
    }

    // Wave-level reduce (64 lanes), then cross-wave via LDS.
#pragma unroll
    for (int off = 32; off > 0; off >>= 1)
        ss += __shfl_down(ss, off, 64);

    __shared__ float sred[BLOCK / 64];
    __shared__ float sinv;
    const int wave = tid >> 6;
    const int lane = tid & 63;
    if (lane == 0) sred[wave] = ss;
    __syncthreads();
    if (tid == 0) {
        float tot = 0.0f;
#pragma unroll
        for (int i = 0; i < BLOCK / 64; ++i) tot += sred[i];
        sinv = rsqrtf(tot * (1.0f / (float)DIM) + 1e-6f);
    }
    __syncthreads();
    const float inv = sinv;

    // Pass 2 (pure write): h, out = h*inv*w, and the zero pad.
#pragma unroll
    for (int it = 0; it < ITERS; ++it) {
        const int i = tid + it * BLOCK;
        if (i < VEC4) {
            const float4 hv = h[it];
            nt_store4(&hr[i], hv);
            const float4 wv4 = wv[i];
            float4 o;
            o.x = hv.x * inv * wv4.x;
            o.y = hv.y * inv * wv4.y;
            o.z = hv.z * inv * wv4.z;
            o.w = hv.w * inv * wv4.w;
            nt_store4(&orow[i], o);
        }
    }

    // Zero-pad columns [3584, 4096): 128 float4 per row.
    if (tid < PAD4) {
        nt_store4(&orow[VEC4 + tid], make_float4(0.0f, 0.0f, 0.0f, 0.0f));
    }
}

extern "C" void kernel_launch(void* const* d_in, const int* in_sizes, int n_in,
                              void* d_out, int out_size, void* d_ws, size_t ws_size,
                              hipStream_t stream) {
    const float* x = (const float*)d_in[0];
    const float* res = (const float*)d_in[1];
    const float* w = (const float*)d_in[2];
    float* out = (float*)d_out;                       // [M][NOUT]
    float* hout = out + (size_t)M_ROWS * NOUT;        // [M][DIM]

    fused_add_rmsnorm_pad<<<M_ROWS, BLOCK, 0, stream>>>(x, res, w, out, hout);
}

// Round 4
// 167.336 us; speedup vs baseline: 1.0133x; 1.0133x over previous
//
#include <hip/hip_runtime.h>

// Fused: h = x + residual; out = h * rsqrt(mean(h^2)+eps) * w, zero-padded
// to 4096 cols. d_out layout: out[16384][4096] fp32, then h[16384][3584] fp32.
// R2: non-temporal loads/stores on all streaming traffic.
// R4: BLOCK=128 exact decomposition — 896 float4 = 128x7, pad 128 float4 =
//     128x1. Zero predication, 2-wave reduction, 16 blocks/CU resident,
//     7-deep per-thread load ILP.

#define M_ROWS 16384
#define DIM 3584
#define NOUT 4096
#define VEC4 (DIM / 4)          // 896 float4 per row
#define PAD4 ((NOUT - DIM) / 4) // 128 float4 of zeros per row
#define BLOCK 128
#define ITERS (VEC4 / BLOCK)    // 7, exact

__device__ __forceinline__ float4 nt_load4(const float4* p) {
    float4 v;
    v.x = __builtin_nontemporal_load(&p->x);
    v.y = __builtin_nontemporal_load(&p->y);
    v.z = __builtin_nontemporal_load(&p->z);
    v.w = __builtin_nontemporal_load(&p->w);
    return v;
}

__device__ __forceinline__ void nt_store4(float4* p, float4 v) {
    __builtin_nontemporal_store(v.x, &p->x);
    __builtin_nontemporal_store(v.y, &p->y);
    __builtin_nontemporal_store(v.z, &p->z);
    __builtin_nontemporal_store(v.w, &p->w);
}

__global__ __launch_bounds__(BLOCK) void fused_add_rmsnorm_pad(
    const float* __restrict__ x,
    const float* __restrict__ res,
    const float* __restrict__ w,
    float* __restrict__ out,   // [M][NOUT]
    float* __restrict__ hout)  // [M][DIM]
{
    const int row = blockIdx.x;
    const int tid = threadIdx.x;

    const float4* __restrict__ xr = reinterpret_cast<const float4*>(x + (size_t)row * DIM);
    const float4* __restrict__ rr = reinterpret_cast<const float4*>(res + (size_t)row * DIM);
    const float4* __restrict__ wv = reinterpret_cast<const float4*>(w);
    float4* __restrict__ hr = reinterpret_cast<float4*>(hout + (size_t)row * DIM);
    float4* __restrict__ orow = reinterpret_cast<float4*>(out + (size_t)row * NOUT);

    // Pass 1: h = x + res (store h, keep in regs), accumulate sum(h^2).
    // 7 exact iterations, no predication.
    float4 h[ITERS];
    float ss = 0.0f;
#pragma unroll
    for (int it = 0; it < ITERS; ++it) {
        const int i = tid + it * BLOCK;
        const float4 a = nt_load4(&xr[i]);
        const float4 b = nt_load4(&rr[i]);
        float4 hv;
        hv.x = a.x + b.x;
        hv.y = a.y + b.y;
        hv.z = a.z + b.z;
        hv.w = a.w + b.w;
        h[it] = hv;
        nt_store4(&hr[i], hv);
        ss += hv.x * hv.x + hv.y * hv.y + hv.z * hv.z + hv.w * hv.w;
    }

    // Wave reduce (64 lanes) then single cross-wave exchange (2 waves).
#pragma unroll
    for (int off = 32; off > 0; off >>= 1)
        ss += __shfl_down(ss, off, 64);

    __shared__ float sred[2];
    const int wave = tid >> 6;
    const int lane = tid & 63;
    if (lane == 0) sred[wave] = ss;
    __syncthreads();
    const float tot = sred[0] + sred[1];
    const float inv = rsqrtf(tot * (1.0f / (float)DIM) + 1e-6f);

    // Pass 2: out = h * inv * w (h from regs, w L1/L2-cached).
#pragma unroll
    for (int it = 0; it < ITERS; ++it) {
        const int i = tid + it * BLOCK;
        const float4 hv = h[it];
        const float4 wv4 = wv[i];
        float4 o;
        o.x = hv.x * inv * wv4.x;
        o.y = hv.y * inv * wv4.y;
        o.z = hv.z * inv * wv4.z;
        o.w = hv.w * inv * wv4.w;
        nt_store4(&orow[i], o);
    }

    // Zero-pad columns [3584, 4096): exactly one float4 per thread.
    nt_store4(&orow[VEC4 + tid], make_float4(0.0f, 0.0f, 0.0f, 0.0f));
}

extern "C" void kernel_launch(void* const* d_in, const int* in_sizes, int n_in,
                              void* d_out, int out_size, void* d_ws, size_t ws_size,
                              hipStream_t stream) {
    const float* x = (const float*)d_in[0];
    const float* res = (const float*)d_in[1];
    const float* w = (const float*)d_in[2];
    float* out = (float*)d_out;                       // [M][NOUT]
    float* hout = out + (size_t)M_ROWS * NOUT;        // [M][DIM]

    fused_add_rmsnorm_pad<<<M_ROWS, BLOCK, 0, stream>>>(x, res, w, out, hout);
}